// Round 4
// baseline (627.037 us; speedup 1.0000x reference)
//
#include <hip/hip_runtime.h>

// out = (B @ x_src) @ W  — CSR build, then fused edge-parallel gather (LDS fp32
// atomics) + bf16 MFMA per 32-row block.
//   wtrans:  Wt_bf16[n][k] = bf16(W[k][n])
//   hist/scan/fill: CSR with packed (row_local<<18 | col)  [N=200000 < 2^18]
//   fused:   block b owns rows [32b,32b+32) == CSR edges [off[r0],off[r0+32)).
//            Waves consume edges; each edge = full-wave gather of x_src row,
//            ds_add_f32 into fp32 LDS tile; then fp32->bf16 swizzled tile;
//            then 8 K-steps of mfma_f32_16x16x32_bf16 vs Wt; fp32 out.

typedef short bf16x8 __attribute__((ext_vector_type(8)));
typedef float f32x4  __attribute__((ext_vector_type(4)));

#define BM 32

static __device__ __forceinline__ unsigned short f2bf(float f) {
    union { float f; unsigned u; } a; a.f = f;
    unsigned r = a.u + 0x7FFFu + ((a.u >> 16) & 1u);   // RNE
    return (unsigned short)(r >> 16);
}

__global__ __launch_bounds__(256) void wtrans_kernel(
    const float* __restrict__ W, unsigned short* __restrict__ Wt)
{
    int k = blockIdx.x;
    int n = threadIdx.x;
    Wt[(size_t)n * 256 + k] = f2bf(W[(size_t)k * 256 + n]);
}

__global__ __launch_bounds__(256) void hist_kernel(
    const int* __restrict__ b_rows, int* __restrict__ cnt, int nnz)
{
    int i = blockIdx.x * 256 + threadIdx.x;
    if (i < nnz) atomicAdd(&cnt[b_rows[i]], 1);
}

__global__ __launch_bounds__(1024) void scan_part_kernel(
    const int* __restrict__ cnt, int* __restrict__ partials, int M)
{
    int tid = threadIdx.x;
    int base = blockIdx.x * 4096;
    int s = 0;
    #pragma unroll
    for (int k = 0; k < 4; ++k) {
        int i = base + k * 1024 + tid;
        if (i < M) s += cnt[i];
    }
    #pragma unroll
    for (int d = 1; d < 64; d <<= 1) s += __shfl_xor(s, d);
    __shared__ int wsum[16];
    int lane = tid & 63, wid = tid >> 6;
    if (lane == 0) wsum[wid] = s;
    __syncthreads();
    if (tid == 0) {
        int t = 0;
        #pragma unroll
        for (int w = 0; w < 16; ++w) t += wsum[w];
        partials[blockIdx.x] = t;
    }
}

__global__ __launch_bounds__(64) void scan_mid_kernel(
    int* __restrict__ partials, int* __restrict__ off, int np, int M)
{
    int lane = threadIdx.x;
    int v = (lane < np) ? partials[lane] : 0;
    int x = v;
    #pragma unroll
    for (int d = 1; d < 64; d <<= 1) { int y = __shfl_up(x, d); if (lane >= d) x += y; }
    if (lane < np) partials[lane] = x - v;
    if (lane == 63) off[M] = x;
}

__global__ __launch_bounds__(1024) void scan_apply_kernel(
    const int* __restrict__ cnt, const int* __restrict__ partials,
    int* __restrict__ off, int* __restrict__ cursor, int M)
{
    int tid = threadIdx.x;
    int base = blockIdx.x * 4096 + tid * 4;
    int4 v = make_int4(0, 0, 0, 0);
    if (base + 3 < M) v = *reinterpret_cast<const int4*>(cnt + base);
    else {
        if (base + 0 < M) v.x = cnt[base + 0];
        if (base + 1 < M) v.y = cnt[base + 1];
        if (base + 2 < M) v.z = cnt[base + 2];
    }
    int s1 = v.x + v.y, s2 = s1 + v.z, tsum = s2 + v.w;
    int x = tsum;
    int lane = tid & 63, wid = tid >> 6;
    #pragma unroll
    for (int d = 1; d < 64; d <<= 1) { int y = __shfl_up(x, d); if (lane >= d) x += y; }
    __shared__ int wsum[16];
    if (lane == 63) wsum[wid] = x;
    __syncthreads();
    if (wid == 0 && lane < 16) {
        int w = wsum[lane];
        int xx = w;
        #pragma unroll
        for (int d = 1; d < 16; d <<= 1) { int y = __shfl_up(xx, d); if (lane >= d) xx += y; }
        wsum[lane] = xx - w;
    }
    __syncthreads();
    int excl = (x - tsum) + wsum[wid] + partials[blockIdx.x];
    int o0 = excl, o1 = excl + v.x, o2 = excl + s1, o3 = excl + s2;
    if (base + 0 < M) { off[base + 0] = o0; cursor[base + 0] = o0; }
    if (base + 1 < M) { off[base + 1] = o1; cursor[base + 1] = o1; }
    if (base + 2 < M) { off[base + 2] = o2; cursor[base + 2] = o2; }
    if (base + 3 < M) { off[base + 3] = o3; cursor[base + 3] = o3; }
}

__global__ __launch_bounds__(256) void fill_kernel(
    const float* __restrict__ b_vals, const int* __restrict__ b_rows,
    const int* __restrict__ b_cols, int* __restrict__ cursor,
    unsigned int* __restrict__ csr_packed, float* __restrict__ csr_val, int nnz)
{
    int i = blockIdx.x * 256 + threadIdx.x;
    if (i < nnz) {
        int r = b_rows[i];
        int pos = atomicAdd(&cursor[r], 1);
        csr_packed[pos] = (unsigned)b_cols[i] | ((unsigned)(r & (BM - 1)) << 18);
        csr_val[pos] = b_vals[i];
    }
}

__global__ __launch_bounds__(256) void fused_kernel(
    const float* __restrict__ x_src, const float* __restrict__ csr_val,
    const unsigned int* __restrict__ csr_packed, const int* __restrict__ off,
    const unsigned short* __restrict__ Wt, float* __restrict__ out, int M)
{
    __shared__ __align__(16) float accf[BM * 256];          // 32 KB fp32 accum
    __shared__ __align__(16) unsigned char Ab[BM * 512];    // 16 KB bf16 A, swizzled

    int tid = threadIdx.x;
    int lane = tid & 63, wid = tid >> 6;
    int r0 = blockIdx.x * BM;

    // zero the fp32 accumulator
    f32x4* az = reinterpret_cast<f32x4*>(accf);
    #pragma unroll
    for (int i = 0; i < (BM * 256 / 4) / 256; ++i)
        az[i * 256 + tid] = (f32x4){0.f, 0.f, 0.f, 0.f};
    __syncthreads();

    int s_blk = off[r0];
    int e_blk = off[min(r0 + BM, M)];

    // ---- edge-parallel gather: wave takes 2 consecutive edges per iteration
    for (int j0 = s_blk + wid * 2; j0 < e_blk; j0 += 8) {
        int j1 = j0 + 1;
        bool has1 = (j1 < e_blk);
        unsigned p0 = csr_packed[j0];
        float    v0 = csr_val[j0];
        unsigned p1 = has1 ? csr_packed[j1] : p0;
        float    v1 = has1 ? csr_val[j1] : 0.f;
        int c0 = (int)(p0 & 0x3FFFFu), a0 = (int)(p0 >> 18);
        int c1 = (int)(p1 & 0x3FFFFu), a1 = (int)(p1 >> 18);

        const float* s0 = x_src + (size_t)c0 * 256 + lane;
        const float* s1 = x_src + (size_t)c1 * 256 + lane;
        float g00 = s0[0], g01 = s0[64], g02 = s0[128], g03 = s0[192];
        float g10 = s1[0], g11 = s1[64], g12 = s1[128], g13 = s1[192];

        float* d0 = accf + a0 * 256 + lane;   // bank = lane%32 -> 2-way (free)
        float* d1 = accf + a1 * 256 + lane;
        atomicAdd(d0 +   0, v0 * g00);
        atomicAdd(d0 +  64, v0 * g01);
        atomicAdd(d0 + 128, v0 * g02);
        atomicAdd(d0 + 192, v0 * g03);
        atomicAdd(d1 +   0, v1 * g10);
        atomicAdd(d1 +  64, v1 * g11);
        atomicAdd(d1 + 128, v1 * g12);
        atomicAdd(d1 + 192, v1 * g13);
    }
    __syncthreads();

    // ---- fp32 -> bf16 conversion into swizzled A tile
    for (int e = tid * 2; e < BM * 256; e += 512) {
        int row = e >> 8, ch = e & 255;
        float2 f = *reinterpret_cast<const float2*>(accf + row * 256 + ch);
        unsigned u = (unsigned)f2bf(f.x) | ((unsigned)f2bf(f.y) << 16);
        int byte = row * 512 + ((ch * 2) ^ ((row & 7) << 4));
        *reinterpret_cast<unsigned*>(Ab + byte) = u;
    }
    __syncthreads();

    // ---- MFMA: wave computes rows [r0, r0+32) x cols [64*wid, 64*wid+64)
    f32x4 acc[2][4] = {};
    const char* wt = reinterpret_cast<const char*>(Wt);   // [n][k] bf16
    int nbase = wid * 64;
    int arow = lane & 15;
    int kgrp = (lane >> 4) * 16;      // byte offset of lane's 8-bf16 k-run

    for (int s = 0; s < 8; ++s) {
        bf16x8 a[2], b[4];
        #pragma unroll
        for (int m = 0; m < 2; ++m) {
            int row = m * 16 + arow;
            int byte = row * 512 + ((s * 64 + kgrp) ^ ((row & 7) << 4));
            a[m] = *reinterpret_cast<const bf16x8*>(Ab + byte);
        }
        #pragma unroll
        for (int t = 0; t < 4; ++t) {
            int n = nbase + t * 16 + arow;
            b[t] = *reinterpret_cast<const bf16x8*>(wt + (size_t)n * 512 + s * 64 + kgrp);
        }
        #pragma unroll
        for (int m = 0; m < 2; ++m)
            #pragma unroll
            for (int t = 0; t < 4; ++t)
                acc[m][t] = __builtin_amdgcn_mfma_f32_16x16x32_bf16(a[m], b[t], acc[m][t], 0, 0, 0);
    }

    // ---- epilogue
    #pragma unroll
    for (int m = 0; m < 2; ++m) {
        int rowb = r0 + m * 16 + (lane >> 4) * 4;
        #pragma unroll
        for (int r = 0; r < 4; ++r) {
            if (rowb + r < M) {
                #pragma unroll
                for (int t = 0; t < 4; ++t)
                    out[(size_t)(rowb + r) * 256 + nbase + t * 16 + arow] = acc[m][t][r];
            }
        }
    }
}

extern "C" void kernel_launch(void* const* d_in, const int* in_sizes, int n_in,
                              void* d_out, int out_size, void* d_ws, size_t ws_size,
                              hipStream_t stream) {
    const float* x_src  = (const float*)d_in[0];
    const float* W      = (const float*)d_in[1];
    const float* b_vals = (const float*)d_in[2];
    const int*   b_rows = (const int*)d_in[3];
    const int*   b_cols = (const int*)d_in[4];

    const int C = 256;
    const int M = out_size / C;
    const int nnz = in_sizes[2];

    char* ws = (char*)d_ws;
    unsigned short* Wt = (unsigned short*)ws;           ws += 256 * 256 * 2;
    int*   cnt     = (int*)ws;                          ws += (size_t)M * 4;
    int*   off     = (int*)ws;                          ws += (size_t)(M + 1) * 4;
    int*   cursor  = (int*)ws;                          ws += (size_t)M * 4;
    int*   partials= (int*)ws;                          ws += 64 * 4;
    unsigned int* csr_packed = (unsigned int*)ws;       ws += (size_t)nnz * 4;
    float* csr_val = (float*)ws;                        ws += (size_t)nnz * 4;

    float* out = (float*)d_out;

    hipMemsetAsync(cnt, 0, (size_t)M * 4, stream);

    wtrans_kernel<<<256, 256, 0, stream>>>(W, Wt);

    int nblk_nnz = (nnz + 255) / 256;
    hist_kernel<<<nblk_nnz, 256, 0, stream>>>(b_rows, cnt, nnz);

    int nb = (M + 4095) / 4096;
    scan_part_kernel<<<nb, 1024, 0, stream>>>(cnt, partials, M);
    scan_mid_kernel<<<1, 64, 0, stream>>>(partials, off, nb, M);
    scan_apply_kernel<<<nb, 1024, 0, stream>>>(cnt, partials, off, cursor, M);

    fill_kernel<<<nblk_nnz, 256, 0, stream>>>(b_vals, b_rows, b_cols, cursor,
                                              csr_packed, csr_val, nnz);

    int nblk_fused = (M + BM - 1) / BM;
    fused_kernel<<<nblk_fused, 256, 0, stream>>>(x_src, csr_val, csr_packed, off,
                                                 Wt, out, M);
}

// Round 5
// 209.450 us; speedup vs baseline: 2.9937x; 2.9937x over previous
//
#include <hip/hip_runtime.h>

// out = (B @ x_src) @ W
//   wtrans:        Wt_bf16[n][k] = bf16(W[k][n])
//   hist/scan/fill: CSR build (cnt -> off -> csr_col/csr_val)
//   per row-chunk (sized by ws_size):
//     gather: wave per row, 8-deep batched independent gathers, register fp32
//             accum, write tmp row as bf16
//     gemm:   LDS-free MFMA: A-frags direct from tmp (full-64B-line reads),
//             B-frags from L2-resident Wt, fp32 out

typedef short bf16x8 __attribute__((ext_vector_type(8)));
typedef float f32x4  __attribute__((ext_vector_type(4)));

static __device__ __forceinline__ unsigned short f2bf(float f) {
    union { float f; unsigned u; } a; a.f = f;
    unsigned r = a.u + 0x7FFFu + ((a.u >> 16) & 1u);   // RNE
    return (unsigned short)(r >> 16);
}

__global__ __launch_bounds__(256) void wtrans_kernel(
    const float* __restrict__ W, unsigned short* __restrict__ Wt)
{
    int k = blockIdx.x;
    int n = threadIdx.x;
    Wt[(size_t)n * 256 + k] = f2bf(W[(size_t)k * 256 + n]);
}

__global__ __launch_bounds__(256) void hist_kernel(
    const int* __restrict__ b_rows, int* __restrict__ cnt, int nnz)
{
    int i = blockIdx.x * 256 + threadIdx.x;
    if (i < nnz) atomicAdd(&cnt[b_rows[i]], 1);
}

__global__ __launch_bounds__(1024) void scan_part_kernel(
    const int* __restrict__ cnt, int* __restrict__ partials, int M)
{
    int tid = threadIdx.x;
    int base = blockIdx.x * 4096;
    int s = 0;
    #pragma unroll
    for (int k = 0; k < 4; ++k) {
        int i = base + k * 1024 + tid;
        if (i < M) s += cnt[i];
    }
    #pragma unroll
    for (int d = 1; d < 64; d <<= 1) s += __shfl_xor(s, d);
    __shared__ int wsum[16];
    int lane = tid & 63, wid = tid >> 6;
    if (lane == 0) wsum[wid] = s;
    __syncthreads();
    if (tid == 0) {
        int t = 0;
        #pragma unroll
        for (int w = 0; w < 16; ++w) t += wsum[w];
        partials[blockIdx.x] = t;
    }
}

__global__ __launch_bounds__(64) void scan_mid_kernel(
    int* __restrict__ partials, int* __restrict__ off, int np, int M)
{
    int lane = threadIdx.x;
    int v = (lane < np) ? partials[lane] : 0;
    int x = v;
    #pragma unroll
    for (int d = 1; d < 64; d <<= 1) { int y = __shfl_up(x, d); if (lane >= d) x += y; }
    if (lane < np) partials[lane] = x - v;
    if (lane == 63) off[M] = x;
}

__global__ __launch_bounds__(1024) void scan_apply_kernel(
    const int* __restrict__ cnt, const int* __restrict__ partials,
    int* __restrict__ off, int* __restrict__ cursor, int M)
{
    int tid = threadIdx.x;
    int base = blockIdx.x * 4096 + tid * 4;
    int4 v = make_int4(0, 0, 0, 0);
    if (base + 3 < M) v = *reinterpret_cast<const int4*>(cnt + base);
    else {
        if (base + 0 < M) v.x = cnt[base + 0];
        if (base + 1 < M) v.y = cnt[base + 1];
        if (base + 2 < M) v.z = cnt[base + 2];
    }
    int s1 = v.x + v.y, s2 = s1 + v.z, tsum = s2 + v.w;
    int x = tsum;
    int lane = tid & 63, wid = tid >> 6;
    #pragma unroll
    for (int d = 1; d < 64; d <<= 1) { int y = __shfl_up(x, d); if (lane >= d) x += y; }
    __shared__ int wsum[16];
    if (lane == 63) wsum[wid] = x;
    __syncthreads();
    if (wid == 0 && lane < 16) {
        int w = wsum[lane];
        int xx = w;
        #pragma unroll
        for (int d = 1; d < 16; d <<= 1) { int y = __shfl_up(xx, d); if (lane >= d) xx += y; }
        wsum[lane] = xx - w;
    }
    __syncthreads();
    int excl = (x - tsum) + wsum[wid] + partials[blockIdx.x];
    int o0 = excl, o1 = excl + v.x, o2 = excl + s1, o3 = excl + s2;
    if (base + 0 < M) { off[base + 0] = o0; cursor[base + 0] = o0; }
    if (base + 1 < M) { off[base + 1] = o1; cursor[base + 1] = o1; }
    if (base + 2 < M) { off[base + 2] = o2; cursor[base + 2] = o2; }
    if (base + 3 < M) { off[base + 3] = o3; cursor[base + 3] = o3; }
}

__global__ __launch_bounds__(256) void fill_kernel(
    const float* __restrict__ b_vals, const int* __restrict__ b_rows,
    const int* __restrict__ b_cols, int* __restrict__ cursor,
    int* __restrict__ csr_col, float* __restrict__ csr_val, int nnz)
{
    int i = blockIdx.x * 256 + threadIdx.x;
    if (i < nnz) {
        int r = b_rows[i];
        int pos = atomicAdd(&cursor[r], 1);
        csr_col[pos] = b_cols[i];
        csr_val[pos] = b_vals[i];
    }
}

// One wave per row; 8-deep batched independent gathers; bf16 row out.
__global__ __launch_bounds__(256) void gather_kernel(
    const float* __restrict__ x_src, const float* __restrict__ csr_val,
    const int* __restrict__ csr_col, const int* __restrict__ off,
    unsigned short* __restrict__ tmp, int r_base, int nrows)
{
    int wrow = blockIdx.x * 4 + (threadIdx.x >> 6);
    if (wrow >= nrows) return;
    int lane = threadIdx.x & 63;
    int row = r_base + wrow;

    int s = off[row], e = off[row + 1];
    const float4* x4 = reinterpret_cast<const float4*>(x_src);
    float4 acc = make_float4(0.f, 0.f, 0.f, 0.f);

    for (int j = s; j < e; j += 8) {
        int   c[8]; float v[8];
        #pragma unroll
        for (int t = 0; t < 8; ++t) {
            int jj = j + t;
            int jc = (jj < e) ? jj : s;           // safe index
            c[t] = csr_col[jc];
            v[t] = (jj < e) ? csr_val[jc] : 0.f;
        }
        float4 xs[8];
        #pragma unroll
        for (int t = 0; t < 8; ++t)
            xs[t] = x4[(size_t)c[t] * 64 + lane]; // 8 independent 1KB gathers
        #pragma unroll
        for (int t = 0; t < 8; ++t) {
            acc.x += v[t] * xs[t].x; acc.y += v[t] * xs[t].y;
            acc.z += v[t] * xs[t].z; acc.w += v[t] * xs[t].w;
        }
    }

    ushort4 h;
    h.x = f2bf(acc.x); h.y = f2bf(acc.y); h.z = f2bf(acc.z); h.w = f2bf(acc.w);
    *reinterpret_cast<ushort4*>(tmp + (size_t)wrow * 256 + lane * 4) = h;
}

// LDS-free MFMA GEMM: out[r_base+rows, :] = tmp @ Wt^T (Wt is [n][k]).
__global__ __launch_bounds__(256) void gemm_kernel(
    const unsigned short* __restrict__ tmp, const unsigned short* __restrict__ Wt,
    float* __restrict__ out, int r_base, int nrows)
{
    int lane = threadIdx.x & 63, wid = threadIdx.x >> 6;
    int m0 = blockIdx.x * 64;                  // chunk-local row base
    int nbase = wid * 64;
    int arow = lane & 15;
    int kbyte = (lane >> 4) * 16;

    const char* at = reinterpret_cast<const char*>(tmp);
    const char* wt = reinterpret_cast<const char*>(Wt);

    f32x4 acc[4][4] = {};
    for (int s = 0; s < 8; ++s) {
        bf16x8 a[4], b[4];
        #pragma unroll
        for (int m = 0; m < 4; ++m) {
            int row = m0 + m * 16 + arow;      // 16 rows x 64B lines, 100% utilized
            a[m] = *reinterpret_cast<const bf16x8*>(at + (size_t)row * 512 + s * 64 + kbyte);
        }
        #pragma unroll
        for (int t = 0; t < 4; ++t) {
            int n = nbase + t * 16 + arow;
            b[t] = *reinterpret_cast<const bf16x8*>(wt + (size_t)n * 512 + s * 64 + kbyte);
        }
        #pragma unroll
        for (int m = 0; m < 4; ++m)
            #pragma unroll
            for (int t = 0; t < 4; ++t)
                acc[m][t] = __builtin_amdgcn_mfma_f32_16x16x32_bf16(a[m], b[t], acc[m][t], 0, 0, 0);
    }

    #pragma unroll
    for (int m = 0; m < 4; ++m) {
        int rl = m0 + m * 16 + (lane >> 4) * 4;
        #pragma unroll
        for (int r = 0; r < 4; ++r) {
            if (rl + r < nrows) {
                #pragma unroll
                for (int t = 0; t < 4; ++t)
                    out[(size_t)(r_base + rl + r) * 256 + nbase + t * 16 + arow] = acc[m][t][r];
            }
        }
    }
}

extern "C" void kernel_launch(void* const* d_in, const int* in_sizes, int n_in,
                              void* d_out, int out_size, void* d_ws, size_t ws_size,
                              hipStream_t stream) {
    const float* x_src  = (const float*)d_in[0];
    const float* W      = (const float*)d_in[1];
    const float* b_vals = (const float*)d_in[2];
    const int*   b_rows = (const int*)d_in[3];
    const int*   b_cols = (const int*)d_in[4];

    const int C = 256;
    const int M = out_size / C;
    const int nnz = in_sizes[2];

    char* ws = (char*)d_ws;
    unsigned short* Wt = (unsigned short*)ws;           ws += 256 * 256 * 2;
    int*   cnt     = (int*)ws;                          ws += (size_t)M * 4;
    int*   off     = (int*)ws;                          ws += (size_t)(M + 1) * 4;
    int*   cursor  = (int*)ws;                          ws += (size_t)M * 4;
    int*   partials= (int*)ws;                          ws += 64 * 4;
    int*   csr_col = (int*)ws;                          ws += (size_t)nnz * 4;
    float* csr_val = (float*)ws;                        ws += (size_t)nnz * 4;
    // align tmp to 64B
    ws = (char*)(((size_t)ws + 63) & ~(size_t)63);
    unsigned short* tmp = (unsigned short*)ws;

    size_t used = (size_t)(ws - (char*)d_ws);
    size_t avail = (ws_size > used) ? (ws_size - used) : 0;
    // tmp holds chunk_rows+64 padded rows of 512B
    long long cr = (long long)(avail / 512) - 64;
    if (cr < 64) cr = 64;                     // last-resort minimum
    if (cr > M) cr = M;
    int chunk_rows = (int)(cr & ~63LL);
    if (chunk_rows < 64) chunk_rows = 64;

    float* out = (float*)d_out;

    hipMemsetAsync(cnt, 0, (size_t)M * 4, stream);

    wtrans_kernel<<<256, 256, 0, stream>>>(W, Wt);

    int nblk_nnz = (nnz + 255) / 256;
    hist_kernel<<<nblk_nnz, 256, 0, stream>>>(b_rows, cnt, nnz);

    int nb = (M + 4095) / 4096;
    scan_part_kernel<<<nb, 1024, 0, stream>>>(cnt, partials, M);
    scan_mid_kernel<<<1, 64, 0, stream>>>(partials, off, nb, M);
    scan_apply_kernel<<<nb, 1024, 0, stream>>>(cnt, partials, off, cursor, M);

    fill_kernel<<<nblk_nnz, 256, 0, stream>>>(b_vals, b_rows, b_cols, cursor,
                                              csr_col, csr_val, nnz);

    for (int r0 = 0; r0 < M; r0 += chunk_rows) {
        int nr = (M - r0 < chunk_rows) ? (M - r0) : chunk_rows;
        gather_kernel<<<(nr + 3) / 4, 256, 0, stream>>>(
            x_src, csr_val, csr_col, off, tmp, r0, nr);
        gemm_kernel<<<(nr + 63) / 64, 256, 0, stream>>>(tmp, Wt, out, r0, nr);
    }
}